// Round 1
// baseline (68.501 us; speedup 1.0000x reference)
//
#include <hip/hip_runtime.h>

#define N_TOK 8192
#define D_DIM 1024
#define E_NUM 8
#define D4 (D_DIM / 4)

// Kernel 1: per-expert prefix scan over hot_mask -> gather map (src), tags, counts.
// One block per expert, 256 threads, 32 contiguous tokens per thread.
__global__ __launch_bounds__(256) void dispatch_scan_kernel(
    const int* __restrict__ hot_mask,   // [N, E]
    int* __restrict__ src,              // [E, N]  (workspace): token idx or -1
    float* __restrict__ out_tags,       // [E, N]  (in d_out)
    float* __restrict__ out_counts)     // [E]     (in d_out)
{
    const int e = blockIdx.x;
    const int t = threadIdx.x;
    constexpr int TPT = N_TOK / 256;    // 32 tokens per thread

    __shared__ int lds[256];

    const int base = t * TPT;
    int m[TPT];
    int tot = 0;
    #pragma unroll
    for (int i = 0; i < TPT; ++i) {
        m[i] = hot_mask[(size_t)(base + i) * E_NUM + e];
        tot += m[i];
    }

    lds[t] = tot;
    __syncthreads();

    // Hillis-Steele inclusive scan over 256 per-thread totals.
    for (int off = 1; off < 256; off <<= 1) {
        int other = (t >= off) ? lds[t - off] : 0;
        __syncthreads();
        if (t >= off) lds[t] += other;
        __syncthreads();
    }

    const int incl  = lds[t];
    const int excl  = incl - tot;
    const int count = lds[255];

    // Write routed entries: src[e][rank] = n, tag[e][rank] = n.
    int r = excl;
    #pragma unroll
    for (int i = 0; i < TPT; ++i) {
        if (m[i]) {
            const int n = base + i;
            src[(size_t)e * N_TOK + r]      = n;
            out_tags[(size_t)e * N_TOK + r] = (float)n;
            ++r;
        }
    }

    // Zero-fill / invalidate pad region [count, N).
    for (int rr = count + t; rr < N_TOK; rr += 256) {
        src[(size_t)e * N_TOK + rr]      = -1;
        out_tags[(size_t)e * N_TOK + rr] = 0.0f;
    }

    if (t == 0) out_counts[e] = (float)count;
}

// Kernel 2: one block per output row (e*N + r). 256 threads x float4 = 1024 floats.
__global__ __launch_bounds__(256) void dispatch_gather_kernel(
    const float4* __restrict__ x,       // [N, D/4]
    const float* __restrict__ score,    // [N, E]
    const int* __restrict__ src,        // [E, N]
    float4* __restrict__ out)           // [E*N, D/4]
{
    const int row = blockIdx.x;         // e * N_TOK + r
    const int e   = row >> 13;          // N_TOK == 8192
    const int c   = threadIdx.x;

    const int n = src[row];             // uniform per block -> scalar load

    float4 v;
    if (n >= 0) {
        const float s = score[(size_t)n * E_NUM + e];   // uniform -> scalar load
        const float4 xv = x[(size_t)n * D4 + c];
        v.x = xv.x * s;
        v.y = xv.y * s;
        v.z = xv.z * s;
        v.w = xv.w * s;
    } else {
        v.x = 0.0f; v.y = 0.0f; v.z = 0.0f; v.w = 0.0f;
    }

    out[(size_t)row * D4 + c] = v;
}

extern "C" void kernel_launch(void* const* d_in, const int* in_sizes, int n_in,
                              void* d_out, int out_size, void* d_ws, size_t ws_size,
                              hipStream_t stream) {
    const float* x        = (const float*)d_in[0];
    const int*   hot_mask = (const int*)d_in[1];
    const float* score    = (const float*)d_in[2];

    float* out        = (float*)d_out;
    float* out_data   = out;                                            // [E, N, D]
    float* out_tags   = out + (size_t)E_NUM * N_TOK * D_DIM;            // [E, N]
    float* out_counts = out_tags + (size_t)E_NUM * N_TOK;               // [E]

    int* src = (int*)d_ws;                                              // [E, N] = 256 KB

    dispatch_scan_kernel<<<E_NUM, 256, 0, stream>>>(hot_mask, src, out_tags, out_counts);
    dispatch_gather_kernel<<<E_NUM * N_TOK, 256, 0, stream>>>(
        (const float4*)x, score, src, (float4*)out_data);
}

// Round 2
// 63.030 us; speedup vs baseline: 1.0868x; 1.0868x over previous
//
#include <hip/hip_runtime.h>

#define N_TOK 8192
#define D_DIM 1024
#define E_NUM 8
#define D4 (D_DIM / 4)

// Workspace layout:
//   dest[N][E]  int  : rank of token n within expert e, or -1   (256 KB)
//   counts_i[E] int  : tokens per expert                        (32 B)

// Kernel 1: per-expert prefix scan. 8 blocks (one per expert) x 256 threads,
// 32 contiguous tokens per thread. Writes dest (token-major), tags, counts.
__global__ __launch_bounds__(256) void dispatch_scan_kernel(
    const int* __restrict__ hot_mask,   // [N, E]
    int* __restrict__ dest,             // [N, E] (ws)
    int* __restrict__ counts_i,         // [E]    (ws)
    float* __restrict__ out_tags,       // [E, N]
    float* __restrict__ out_counts)     // [E]
{
    const int e = blockIdx.x;
    const int t = threadIdx.x;
    constexpr int TPT = N_TOK / 256;    // 32

    __shared__ int lds[256];

    const int base = t * TPT;
    int m[TPT];
    int tot = 0;
    #pragma unroll
    for (int i = 0; i < TPT; ++i) {
        m[i] = hot_mask[(size_t)(base + i) * E_NUM + e];
        tot += m[i];
    }

    lds[t] = tot;
    __syncthreads();

    // Hillis-Steele inclusive scan over 256 per-thread totals.
    for (int off = 1; off < 256; off <<= 1) {
        int other = (t >= off) ? lds[t - off] : 0;
        __syncthreads();
        if (t >= off) lds[t] += other;
        __syncthreads();
    }

    const int incl  = lds[t];
    const int excl  = incl - tot;
    const int count = lds[255];

    int r = excl;
    #pragma unroll
    for (int i = 0; i < TPT; ++i) {
        const int n = base + i;
        if (m[i]) {
            dest[(size_t)n * E_NUM + e]     = r;
            out_tags[(size_t)e * N_TOK + r] = (float)n;
            ++r;
        } else {
            dest[(size_t)n * E_NUM + e] = -1;
        }
    }

    // Zero-fill tag pad region [count, N).
    for (int rr = count + t; rr < N_TOK; rr += 256) {
        out_tags[(size_t)e * N_TOK + rr] = 0.0f;
    }

    if (t == 0) {
        counts_i[e]   = count;
        out_counts[e] = (float)count;
    }
}

// Kernel 2 (fused scatter + pad-fill):
//   blocks [0, N)        : token-scatter. Read x[n] once, write to each routed
//                          expert row (coalesced 4 KB row stores).
//   blocks [N, N + E*N)  : row (b - N) = e*N + r; if r >= count[e], zero-fill.
// Output regions are disjoint (scatter writes rows < count, pad writes >= count).
__global__ __launch_bounds__(256) void dispatch_scatter_kernel(
    const float4* __restrict__ x,       // [N, D/4]
    const float* __restrict__ score,    // [N, E]
    const int* __restrict__ dest,       // [N, E]
    const int* __restrict__ counts_i,   // [E]
    float4* __restrict__ out)           // [E*N, D/4]
{
    const int b = blockIdx.x;
    const int c = threadIdx.x;

    if (b < N_TOK) {
        const int n = b;
        const float4 xv = x[(size_t)n * D4 + c];
        #pragma unroll
        for (int e = 0; e < E_NUM; ++e) {
            const int r = dest[(size_t)n * E_NUM + e];   // uniform per block
            if (r >= 0) {
                const float s = score[(size_t)n * E_NUM + e];
                float4 v;
                v.x = xv.x * s;
                v.y = xv.y * s;
                v.z = xv.z * s;
                v.w = xv.w * s;
                out[((size_t)e * N_TOK + r) * D4 + c] = v;
            }
        }
    } else {
        const int row = b - N_TOK;          // e*N + r
        const int e   = row >> 13;
        const int r   = row & (N_TOK - 1);
        if (r >= counts_i[e]) {
            float4 z;
            z.x = 0.0f; z.y = 0.0f; z.z = 0.0f; z.w = 0.0f;
            out[(size_t)row * D4 + c] = z;
        }
    }
}

extern "C" void kernel_launch(void* const* d_in, const int* in_sizes, int n_in,
                              void* d_out, int out_size, void* d_ws, size_t ws_size,
                              hipStream_t stream) {
    const float* x        = (const float*)d_in[0];
    const int*   hot_mask = (const int*)d_in[1];
    const float* score    = (const float*)d_in[2];

    float* out        = (float*)d_out;
    float* out_data   = out;                                  // [E, N, D]
    float* out_tags   = out + (size_t)E_NUM * N_TOK * D_DIM;  // [E, N]
    float* out_counts = out_tags + (size_t)E_NUM * N_TOK;     // [E]

    int* dest     = (int*)d_ws;                               // [N, E]
    int* counts_i = dest + (size_t)N_TOK * E_NUM;             // [E]

    dispatch_scan_kernel<<<E_NUM, 256, 0, stream>>>(
        hot_mask, dest, counts_i, out_tags, out_counts);

    dispatch_scatter_kernel<<<N_TOK + E_NUM * N_TOK, 256, 0, stream>>>(
        (const float4*)x, score, dest, counts_i, (float4*)out_data);
}